// Round 10
// baseline (463.934 us; speedup 1.0000x reference)
//
#include <hip/hip_runtime.h>

#define N_NODES 100000
#define N_EDGES 1600000
#define NB ((N_NODES + 255) >> 8)   // 391 buckets of 256 nodes

// ---------------- CSR build: bucket hist -> scan -> 2-level scatter ----------------

__global__ __launch_bounds__(256) void k_bhist(const int* __restrict__ dst,
                                               int* __restrict__ bucket_cnt, int E) {
    __shared__ int h[NB];
    for (int i = threadIdx.x; i < NB; i += 256) h[i] = 0;
    __syncthreads();
    int c0 = blockIdx.x * 4096, c1 = min(c0 + 4096, E);
    for (int i = c0 + threadIdx.x; i < c1; i += 256)
        atomicAdd(&h[dst[i] >> 8], 1);
    __syncthreads();
    for (int i = threadIdx.x; i < NB; i += 256)
        if (h[i]) atomicAdd(&bucket_cnt[i], h[i]);
}

__global__ void k_bscan(const int* __restrict__ bucket_cnt, int* __restrict__ bucket_base,
                        int* __restrict__ bcur, int* __restrict__ row_start) {
    if (threadIdx.x == 0) {
        int run = 0;
        for (int b = 0; b < NB; b++) {
            bucket_base[b] = run; bcur[b] = run; run += bucket_cnt[b];
        }
        bucket_base[NB] = run;
        row_start[N_NODES] = run;   // == E
    }
}

__global__ __launch_bounds__(256) void k_partA(const int* __restrict__ src,
                                               const int* __restrict__ dst,
                                               int* __restrict__ bcur,
                                               int2* __restrict__ stage, int E) {
    __shared__ int h[NB];
    __shared__ int cur[NB];
    for (int i = threadIdx.x; i < NB; i += 256) h[i] = 0;
    __syncthreads();
    int c0 = blockIdx.x * 4096, c1 = min(c0 + 4096, E);
    for (int i = c0 + threadIdx.x; i < c1; i += 256)
        atomicAdd(&h[dst[i] >> 8], 1);
    __syncthreads();
    for (int b = threadIdx.x; b < NB; b += 256) {
        int c = h[b];
        cur[b] = c ? atomicAdd(&bcur[b], c) : 0;
    }
    __syncthreads();
    for (int i = c0 + threadIdx.x; i < c1; i += 256) {
        int s = src[i], d = dst[i];
        int pos = atomicAdd(&cur[d >> 8], 1);
        stage[pos] = make_int2(s, d);
    }
}

__global__ __launch_bounds__(256) void k_partB1(const int2* __restrict__ stage,
                                                const int* __restrict__ bucket_base,
                                                int* __restrict__ row_start,
                                                float* __restrict__ dis) {
    __shared__ int cnt[256];
    __shared__ int pref[256];
    int b = blockIdx.x;
    int node0 = b << 8;
    int nn = min(256, N_NODES - node0);
    int t = threadIdx.x;
    cnt[t] = 0;
    __syncthreads();
    int e0 = bucket_base[b], e1 = bucket_base[b + 1];
    for (int e = e0 + t; e < e1; e += 256)
        atomicAdd(&cnt[stage[e].y & 255], 1);
    __syncthreads();
    if (t == 0) {
        int run = e0;   // global CSR offset
        for (int i = 0; i < nn; i++) { pref[i] = run; run += cnt[i]; }
    }
    __syncthreads();
    if (t < nn) {
        row_start[node0 + t] = pref[t];
        dis[node0 + t] = rsqrtf((float)(cnt[t] + 1));  // deg includes self-loop
    }
}

__global__ __launch_bounds__(256) void k_partB2(const int2* __restrict__ stage,
                                                const int* __restrict__ bucket_base,
                                                const int* __restrict__ row_start,
                                                const float* __restrict__ dis,
                                                int2* __restrict__ pairs) {
    __shared__ int cur[256];
    int b = blockIdx.x;
    int node0 = b << 8;
    int nn = min(256, N_NODES - node0);
    int t = threadIdx.x;
    if (t < nn) cur[t] = row_start[node0 + t];
    __syncthreads();
    int e0 = bucket_base[b], e1 = bucket_base[b + 1];
    for (int e = e0 + t; e < e1; e += 256) {
        int2 sd = stage[e];
        float c = dis[sd.x] * dis[sd.y];
        int pos = atomicAdd(&cur[sd.y & 255], 1);
        pairs[pos] = make_int2(sd.x, __float_as_int(c));
    }
}

// ---------------- dense H = A @ W: W in LDS, A direct global->reg, prefetched ----------------
template <int IN, int OUT>
__global__ __launch_bounds__(256) void k_gemm(const float* __restrict__ A,
                                              const float* __restrict__ W,
                                              float* __restrict__ H, int n) {
    constexpr int BM = 1024 / (OUT / 4);
    __shared__ float Wl[IN * OUT];
    const int tid = threadIdx.x;
    for (int i = tid * 4; i < IN * OUT; i += 1024)
        *(float4*)&Wl[i] = *(const float4*)&W[i];
    __syncthreads();

    const int row0 = blockIdx.x * BM;
    const int tc = tid % (OUT / 4);
    const int tr = tid / (OUT / 4);

    const float* ar[4];
    int row[4];
#pragma unroll
    for (int i = 0; i < 4; i++) {
        row[i] = row0 + tr * 4 + i;
        ar[i] = A + (size_t)min(row[i], n - 1) * IN;
    }

    float4 acc[4];
    acc[0] = acc[1] = acc[2] = acc[3] = make_float4(0.f, 0.f, 0.f, 0.f);

    float4 av[4];
#pragma unroll
    for (int i = 0; i < 4; i++) av[i] = *(const float4*)(ar[i]);

#pragma unroll 4
    for (int k4 = 0; k4 < IN / 4 - 1; k4++) {
        float4 nx[4], wv[4];
#pragma unroll
        for (int i = 0; i < 4; i++)
            nx[i] = *(const float4*)(ar[i] + (k4 + 1) * 4);   // prefetch next
#pragma unroll
        for (int j = 0; j < 4; j++)
            wv[j] = *(float4*)&Wl[(k4 * 4 + j) * OUT + tc * 4];
#pragma unroll
        for (int i = 0; i < 4; i++) {
            acc[i].x += av[i].x * wv[0].x + av[i].y * wv[1].x + av[i].z * wv[2].x + av[i].w * wv[3].x;
            acc[i].y += av[i].x * wv[0].y + av[i].y * wv[1].y + av[i].z * wv[2].y + av[i].w * wv[3].y;
            acc[i].z += av[i].x * wv[0].z + av[i].y * wv[1].z + av[i].z * wv[2].z + av[i].w * wv[3].z;
            acc[i].w += av[i].x * wv[0].w + av[i].y * wv[1].w + av[i].z * wv[2].w + av[i].w * wv[3].w;
        }
#pragma unroll
        for (int i = 0; i < 4; i++) av[i] = nx[i];
    }
    {   // last k4
        constexpr int k4 = IN / 4 - 1;
        float4 wv[4];
#pragma unroll
        for (int j = 0; j < 4; j++)
            wv[j] = *(float4*)&Wl[(k4 * 4 + j) * OUT + tc * 4];
#pragma unroll
        for (int i = 0; i < 4; i++) {
            acc[i].x += av[i].x * wv[0].x + av[i].y * wv[1].x + av[i].z * wv[2].x + av[i].w * wv[3].x;
            acc[i].y += av[i].x * wv[0].y + av[i].y * wv[1].y + av[i].z * wv[2].y + av[i].w * wv[3].y;
            acc[i].z += av[i].x * wv[0].z + av[i].y * wv[1].z + av[i].z * wv[2].z + av[i].w * wv[3].z;
            acc[i].w += av[i].x * wv[0].w + av[i].y * wv[1].w + av[i].z * wv[2].w + av[i].w * wv[3].w;
        }
    }
#pragma unroll
    for (int i = 0; i < 4; i++)
        if (row[i] < n) *(float4*)&H[(size_t)row[i] * OUT + tc * 4] = acc[i];
}

// ---------------- fused: a = relu(agg64(h) + self + bias); H2 = a @ W ----------------
// Wave per node. Gather: 16 edges in flight. After shfl_xor reduce, EVERY lane
// holds row-chunk (l&15); gemm broadcasts chunks via __shfl and reads W cols
// from LDS (lane-consecutive b32, conflict-free). OUT2=32 splits k across halves.
template <int OUT2>
__global__ __launch_bounds__(256) void k_aggemm(const float* __restrict__ h,
                                                const int2* __restrict__ pairs,
                                                const int* __restrict__ row_start,
                                                const float* __restrict__ dis,
                                                const float* __restrict__ bias,
                                                const float* __restrict__ W,  // [64][OUT2]
                                                float* __restrict__ H2, int n) {
    __shared__ float Wl[64 * OUT2];
    const int tid = threadIdx.x;
    for (int i = tid * 4; i < 64 * OUT2; i += 1024)
        *(float4*)&Wl[i] = *(const float4*)&W[i];
    __syncthreads();

    int node = (blockIdx.x * blockDim.x + tid) >> 6;
    if (node >= n) return;
    int l = tid & 63;
    int u = l >> 4;          // edge slot (4 groups)
    int c = (l & 15) * 4;    // feature chunk
    int e0 = row_start[node], e1 = row_start[node + 1];

    float4 acc = make_float4(0.f, 0.f, 0.f, 0.f);
    for (int e = e0; e < e1; e += 16) {
#pragma unroll
        for (int b = 0; b < 4; b++) {
            int idx = e + b * 4 + u;
            bool v = idx < e1;
            int2 p = pairs[v ? idx : e0];
            float cf = v ? __int_as_float(p.y) : 0.f;
            float4 hv = *(const float4*)&h[(size_t)p.x * 64 + c];
            acc.x += cf * hv.x; acc.y += cf * hv.y;
            acc.z += cf * hv.z; acc.w += cf * hv.w;
        }
    }
#pragma unroll
    for (int m = 16; m < 64; m <<= 1) {
        acc.x += __shfl_xor(acc.x, m);
        acc.y += __shfl_xor(acc.y, m);
        acc.z += __shfl_xor(acc.z, m);
        acc.w += __shfl_xor(acc.w, m);
    }
    // self-loop + bias + relu (replicated across sub-waves)
    float dd = dis[node];
    float s = dd * dd;
    float4 hv = *(const float4*)&h[(size_t)node * 64 + c];
    float4 bv = *(const float4*)&bias[c];
    acc.x = fmaxf(acc.x + s * hv.x + bv.x, 0.f);
    acc.y = fmaxf(acc.y + s * hv.y + bv.y, 0.f);
    acc.z = fmaxf(acc.z + s * hv.z + bv.z, 0.f);
    acc.w = fmaxf(acc.w + s * hv.w + bv.w, 0.f);

    if (OUT2 == 64) {
        float o = 0.f;
#pragma unroll
        for (int c16 = 0; c16 < 16; c16++) {
            float4 v;
            v.x = __shfl(acc.x, c16); v.y = __shfl(acc.y, c16);
            v.z = __shfl(acc.z, c16); v.w = __shfl(acc.w, c16);
            o += v.x * Wl[(4 * c16 + 0) * 64 + l] + v.y * Wl[(4 * c16 + 1) * 64 + l]
               + v.z * Wl[(4 * c16 + 2) * 64 + l] + v.w * Wl[(4 * c16 + 3) * 64 + l];
        }
        H2[(size_t)node * 64 + l] = o;
    } else {  // OUT2 == 32: split k across wave halves
        float o = 0.f;
        int base = (l >> 5) * 8;
        int col = l & 31;
#pragma unroll
        for (int i = 0; i < 8; i++) {
            int cc = base + i;
            float4 v;
            v.x = __shfl(acc.x, cc); v.y = __shfl(acc.y, cc);
            v.z = __shfl(acc.z, cc); v.w = __shfl(acc.w, cc);
            o += v.x * Wl[(4 * cc + 0) * 32 + col] + v.y * Wl[(4 * cc + 1) * 32 + col]
               + v.z * Wl[(4 * cc + 2) * 32 + col] + v.w * Wl[(4 * cc + 3) * 32 + col];
        }
        o += __shfl_xor(o, 32);
        if (l < 32) H2[(size_t)node * 32 + l] = o;
    }
}

// ---------------- final CSR gather aggregation (32-wide), MLP-widened ----------------
template <int OUT, bool RELU>
__global__ __launch_bounds__(256) void k_agg(const float* __restrict__ h,
                                             const int2* __restrict__ pairs,
                                             const int* __restrict__ row_start,
                                             const float* __restrict__ dis,
                                             const float* __restrict__ bias,
                                             float* __restrict__ out, int n) {
    constexpr int GROUPS = 256 / OUT;
    constexpr int LPG = OUT / 4;
    int node = (blockIdx.x * blockDim.x + threadIdx.x) >> 6;
    if (node >= n) return;
    int l = threadIdx.x & 63;
    int u = l / LPG;
    int c = (l % LPG) * 4;
    int e0 = row_start[node], e1 = row_start[node + 1];

    float4 acc = make_float4(0.f, 0.f, 0.f, 0.f);
    for (int e = e0; e < e1; e += 2 * GROUPS) {
        int ia = e + u;
        bool va = ia < e1;
        int2 pa = pairs[va ? ia : e0];
        float ca = va ? __int_as_float(pa.y) : 0.f;
        float4 ha = *(const float4*)&h[(size_t)pa.x * OUT + c];
        int ib = e + GROUPS + u;
        bool vb = ib < e1;
        int2 pb = pairs[vb ? ib : e0];
        float cb = vb ? __int_as_float(pb.y) : 0.f;
        float4 hb = *(const float4*)&h[(size_t)pb.x * OUT + c];
        acc.x += ca * ha.x + cb * hb.x;
        acc.y += ca * ha.y + cb * hb.y;
        acc.z += ca * ha.z + cb * hb.z;
        acc.w += ca * ha.w + cb * hb.w;
    }
#pragma unroll
    for (int m = LPG; m < 64; m <<= 1) {
        acc.x += __shfl_xor(acc.x, m);
        acc.y += __shfl_xor(acc.y, m);
        acc.z += __shfl_xor(acc.z, m);
        acc.w += __shfl_xor(acc.w, m);
    }
    if (l < LPG) {
        float dd = dis[node];
        float s = dd * dd;
        float4 hv = *(const float4*)&h[(size_t)node * OUT + c];
        float4 bv = *(const float4*)&bias[c];
        acc.x += s * hv.x + bv.x;
        acc.y += s * hv.y + bv.y;
        acc.z += s * hv.z + bv.z;
        acc.w += s * hv.w + bv.w;
        if (RELU) {
            acc.x = fmaxf(acc.x, 0.f); acc.y = fmaxf(acc.y, 0.f);
            acc.z = fmaxf(acc.z, 0.f); acc.w = fmaxf(acc.w, 0.f);
        }
        *(float4*)&out[(size_t)node * OUT + c] = acc;
    }
}

// ---------------- launch ----------------

extern "C" void kernel_launch(void* const* d_in, const int* in_sizes, int n_in,
                              void* d_out, int out_size, void* d_ws, size_t ws_size,
                              hipStream_t stream) {
    const float* x  = (const float*)d_in[0];
    const int*   ei = (const int*)d_in[1];   // [2, E] int32
    const float* W1 = (const float*)d_in[2];
    const float* b1 = (const float*)d_in[3];
    const float* W2 = (const float*)d_in[4];
    const float* b2 = (const float*)d_in[5];
    const float* W3 = (const float*)d_in[6];
    const float* b3 = (const float*)d_in[7];

    char* ws = (char*)d_ws;
    int*   bucket_cnt  = (int*)(ws + 0);         // 392*4 B
    int*   bucket_base = (int*)(ws + 2048);      // 392*4 B
    int*   bcur        = (int*)(ws + 4096);      // 392*4 B
    float* dis         = (float*)(ws + 8192);    // 400000 B
    int*   row_start   = (int*)(ws + 408576);    // 400004 B
    int2*  pairs       = (int2*)(ws + 809472);   // 12.8 MB
    float* h           = (float*)(ws + 13609472);// 25.6 MB  (h1, then h3)
    int2*  stage       = (int2*)(ws + 13609472); // aliases h (consumed before gemm1)
    float* a           = (float*)(ws + 39209472);// 25.6 MB  (h2)

    const int* src = ei;
    const int* dst = ei + N_EDGES;

    int echunks = (N_EDGES + 4095) / 4096;   // 391

    hipMemsetAsync(bucket_cnt, 0, (NB + 1) * sizeof(int), stream);
    k_bhist<<<echunks, 256, 0, stream>>>(dst, bucket_cnt, N_EDGES);
    k_bscan<<<1, 64, 0, stream>>>(bucket_cnt, bucket_base, bcur, row_start);
    k_partA<<<echunks, 256, 0, stream>>>(src, dst, bcur, stage, N_EDGES);
    k_partB1<<<NB, 256, 0, stream>>>(stage, bucket_base, row_start, dis);
    k_partB2<<<NB, 256, 0, stream>>>(stage, bucket_base, row_start, dis, pairs);

    int gemm64 = (N_NODES + 63) / 64;
    int aggblk = (N_NODES + 3) / 4;        // 1 node per wave, 4 waves/block

    // layer 1 gemm: h1 = x @ W1
    k_gemm<128, 64><<<gemm64, 256, 0, stream>>>(x, W1, h, N_NODES);
    // fused: h2 = relu(agg(h1)+self+b1) @ W2
    k_aggemm<64><<<aggblk, 256, 0, stream>>>(h, pairs, row_start, dis, b1, W2, a, N_NODES);
    // fused: h3 = relu(agg(h2)+self+b2) @ W3
    k_aggemm<32><<<aggblk, 256, 0, stream>>>(a, pairs, row_start, dis, b2, W3, h, N_NODES);
    // final: out = agg(h3) + self + b3
    k_agg<32, false><<<aggblk, 256, 0, stream>>>(h, pairs, row_start, dis, b3,
                                                 (float*)d_out, N_NODES);
}